// Round 1
// baseline (788.185 us; speedup 1.0000x reference)
//
#include <hip/hip_runtime.h>

#define BATCH 16384
#define NEG 20
#define DIM 128
#define NSCORE (NEG + 1)

__global__ void i2v_zero_ws(float* ws) { ws[0] = 0.0f; }

__global__ __launch_bounds__(256) void i2v_main(
    const int* __restrict__ center,
    const int* __restrict__ pos,
    const int* __restrict__ neg,
    const float* __restrict__ W_in,
    const float* __restrict__ W_out,
    float* __restrict__ ws)
{
    const int wave = threadIdx.x >> 6;         // 0..3
    const int lane = threadIdx.x & 63;
    const int b = blockIdx.x * 4 + wave;       // grid = BATCH/4 exactly

    // center embedding: lane i holds elements [2i, 2i+1] -> one 512B coalesced read/wave
    const int c = center[b];
    const float2 ce = ((const float2*)(W_in + (size_t)c * DIM))[lane];

    float scores[NSCORE];
#pragma unroll
    for (int k = 0; k < NSCORE; ++k) {
        const int idx = (k == 0) ? pos[b] : neg[b * NEG + (k - 1)];
        const float2 w = ((const float2*)(W_out + (size_t)idx * DIM))[lane];
        scores[k] = ce.x * w.x + ce.y * w.y;
    }

    // batched butterfly reduction: every lane ends with the full 21 scores
#pragma unroll
    for (int off = 1; off < 64; off <<= 1) {
#pragma unroll
        for (int k = 0; k < NSCORE; ++k)
            scores[k] += __shfl_xor(scores[k], off, 64);
    }

    // wave-uniform loss computation (all lanes redundantly; no divergence)
    // pos:  -log(sigmoid(+s) + eps)
    // neg:  -log(sigmoid(-s) + eps)
    float loss = 0.0f;
#pragma unroll
    for (int k = 0; k < NSCORE; ++k) {
        const float x = (k == 0) ? scores[k] : -scores[k];
        const float p = 1.0f / (1.0f + expf(-x));   // f32, same overflow behavior as ref
        loss -= logf(p + 1e-10f);
    }

    __shared__ float ls[4];
    if (lane == 0) ls[wave] = loss;
    __syncthreads();
    if (threadIdx.x == 0) {
        atomicAdd(ws, ls[0] + ls[1] + ls[2] + ls[3]);
    }
}

__global__ void i2v_finalize(const float* __restrict__ ws, float* __restrict__ out)
{
    out[0] = ws[0] * (1.0f / (float)BATCH);
}

extern "C" void kernel_launch(void* const* d_in, const int* in_sizes, int n_in,
                              void* d_out, int out_size, void* d_ws, size_t ws_size,
                              hipStream_t stream)
{
    const int*   center = (const int*)d_in[0];
    const int*   pos    = (const int*)d_in[1];
    const int*   neg    = (const int*)d_in[2];
    const float* W_in   = (const float*)d_in[3];
    const float* W_out  = (const float*)d_in[4];
    float* out = (float*)d_out;
    float* ws  = (float*)d_ws;

    i2v_zero_ws<<<1, 1, 0, stream>>>(ws);
    i2v_main<<<BATCH / 4, 256, 0, stream>>>(center, pos, neg, W_in, W_out, ws);
    i2v_finalize<<<1, 1, 0, stream>>>(ws, out);
}